// Round 4
// baseline (607.888 us; speedup 1.0000x reference)
//
#include <hip/hip_runtime.h>
#include <hip/hip_bf16.h>

using bf16 = __hip_bfloat16;

#define B_  64
#define C_  256
#define HD_ 256
#define XS  31
#define XO  29
#define ZS  7
#define ZO  5
#define OSP 25
#define XO2 (XO*XO)    // 841
#define ZO2 (ZO*ZO)    // 25
#define OS2 (OSP*OSP)  // 625
#define EPSF 1e-5f

// LDS strides for fused_pre (v4)
#define XCST 976          // per-channel stride in xt (961 used, 16B-aligned)
#define SRS  36           // st row stride (floats)
#define SCST (29 * SRS)   // 1044 per-channel st stride

typedef __attribute__((ext_vector_type(4))) float f32x4;
typedef __attribute__((ext_vector_type(8))) short s16x8;

__device__ __forceinline__ unsigned short f2bf(float f) {
    union { float f; unsigned int u; } a; a.f = f;
    unsigned int r = a.u + 0x7FFF + ((a.u >> 16) & 1);   // RNE
    return (unsigned short)(r >> 16);
}
__device__ __forceinline__ unsigned int pk2(unsigned short a, unsigned short b) {
    return (unsigned int)a | ((unsigned int)b << 16);
}

// ---------------------------------------------------------------------------
// One-time fp32->bf16 conversion of all GEMM weights into workspace.
// Layout: [head_w 3*65536 | cls_w1 3*65536 | loc_w1 3*65536 | ctr_w1 3*65536]
// ---------------------------------------------------------------------------
__global__ void wconv_k(const float* __restrict__ hw, const float* __restrict__ cw,
                        const float* __restrict__ lw, const float* __restrict__ tw,
                        unsigned short* __restrict__ o)
{
    int i = blockIdx.x * 256 + threadIdx.x;
    if (i >= 4 * 196608) return;
    int seg = i / 196608, r = i - seg * 196608;
    const float* s = (seg == 0) ? hw : (seg == 1) ? cw : (seg == 2) ? lw : tw;
    o[i] = f2bf(s[r]);
}

// ---------------------------------------------------------------------------
// Fused: dw3+BN+ReLU on x-tile and z-tile, then depthwise 5x5 xcorr.
// v4: TWO (b,c) pairs per block (grid x = B*C/2).
// ---------------------------------------------------------------------------
__global__ __launch_bounds__(256) void fused_pre_xcorr(
    const float* __restrict__ x, const float* __restrict__ z,
    const float* __restrict__ w, const float* __restrict__ g,
    const float* __restrict__ bb, const float* __restrict__ mm,
    const float* __restrict__ vv, unsigned short* __restrict__ out,
    int si_base)
{
    const int zs  = blockIdx.y;            // local stage (output buffer)
    const int si  = si_base + zs;          // global stage (inputs)
    const int bc0 = blockIdx.x * 2;        // first of 2 (b,c); same b, c even
    const int tid = threadIdx.x;

    __shared__ float xt[2 * XCST + 8];     // x tiles, linear rows (stride 31)
    __shared__ float st[2 * SCST + 16];    // dw3 features, row stride 36
    __shared__ float zt[2 * 49];
    __shared__ float ktl[2 * 25];
    __shared__ float wtl[2 * 9];
    __shared__ float sprm[4];              // inv0, beta0, inv1, beta1

    // ---- Phase A: coalesced load of both x tiles (1922 consecutive floats)
    const float* xp = x + ((size_t)si * B_ * C_ + bc0) * (XS * XS);
    #pragma unroll
    for (int k2 = 0; k2 < 8; ++k2) {
        int idx = tid + k2 * 256;
        if (idx < 2 * XS * XS) {
            int off = idx + (idx >= XS * XS ? (XCST - XS * XS) : 0);
            xt[off] = xp[idx];
        }
    }
    if (tid < 98) zt[tid] = z[((size_t)si * B_ * C_ + bc0) * 49 + tid];
    if (tid < 18) wtl[tid] = w[((size_t)si * C_ + (bc0 & (C_ - 1))) * 9 + tid];
    if (tid < 2) {
        int cg = si * C_ + (bc0 & (C_ - 1)) + tid;
        float iv = g[cg] * rsqrtf(vv[cg] + EPSF);
        sprm[tid * 2]     = iv;
        sprm[tid * 2 + 1] = bb[cg] - mm[cg] * iv;
    }
    __syncthreads();

    // ---- kernel features (two 5x5 tiles), threads 0..49
    if (tid < 50) {
        int ch = (tid >= 25) ? 1 : 0;
        int l  = tid - ch * 25;
        int oy = l / 5, ox = l - (l / 5) * 5;
        const float* zb = &zt[ch * 49];
        const float* wb = &wtl[ch * 9];
        float a = 0.f;
        #pragma unroll
        for (int dy = 0; dy < 3; ++dy)
            #pragma unroll
            for (int dx = 0; dx < 3; ++dx)
                a += zb[(oy + dy) * ZS + ox + dx] * wb[dy * 3 + dx];
        ktl[ch * 25 + l] = fmaxf(a * sprm[ch * 2] + sprm[ch * 2 + 1], 0.f);
    }

    // ---- Phase B: search features, 2-row x 4-col strips, threads 0..239
    if (tid < 240) {
        int ch    = (tid >= 120) ? 1 : 0;
        int rem   = tid - ch * 120;
        int strip = rem >> 3;              // 0..14  (rows 2s, 2s+1)
        int cgp   = rem & 7;               // 0..7   (cols 4cg..4cg+3)
        int r0    = strip * 2;
        const float* base = &xt[ch * XCST + r0 * XS + cgp * 4];
        const float* wb   = &wtl[ch * 9];
        float w0 = wb[0], w1 = wb[1], w2 = wb[2],
              w3 = wb[3], w4 = wb[4], w5 = wb[5],
              w6 = wb[6], w7 = wb[7], w8 = wb[8];
        const float inv  = sprm[ch * 2];
        const float beta = sprm[ch * 2 + 1];

        float a0 = 0.f, a1 = 0.f, a2 = 0.f, a3 = 0.f;   // row r0
        float b0 = 0.f, b1 = 0.f, b2 = 0.f, b3 = 0.f;   // row r0+1
        #pragma unroll
        for (int dy = 0; dy < 4; ++dy) {
            const float* rp = base + dy * XS;
            float v0 = rp[0], v1 = rp[1], v2 = rp[2],
                  v3 = rp[3], v4 = rp[4], v5 = rp[5];
            if (dy < 3) {
                float u0 = (dy == 0) ? w0 : (dy == 1) ? w3 : w6;
                float u1 = (dy == 0) ? w1 : (dy == 1) ? w4 : w7;
                float u2 = (dy == 0) ? w2 : (dy == 1) ? w5 : w8;
                a0 += v0 * u0 + v1 * u1 + v2 * u2;
                a1 += v1 * u0 + v2 * u1 + v3 * u2;
                a2 += v2 * u0 + v3 * u1 + v4 * u2;
                a3 += v3 * u0 + v4 * u1 + v5 * u2;
            }
            if (dy >= 1) {
                float u0 = (dy == 1) ? w0 : (dy == 2) ? w3 : w6;
                float u1 = (dy == 1) ? w1 : (dy == 2) ? w4 : w7;
                float u2 = (dy == 1) ? w2 : (dy == 2) ? w5 : w8;
                b0 += v0 * u0 + v1 * u1 + v2 * u2;
                b1 += v1 * u0 + v2 * u1 + v3 * u2;
                b2 += v2 * u0 + v3 * u1 + v4 * u2;
                b3 += v3 * u0 + v4 * u1 + v5 * u2;
            }
        }
        float4 ra;
        ra.x = fmaxf(a0 * inv + beta, 0.f);
        ra.y = fmaxf(a1 * inv + beta, 0.f);
        ra.z = fmaxf(a2 * inv + beta, 0.f);
        ra.w = fmaxf(a3 * inv + beta, 0.f);
        *(float4*)&st[ch * SCST + r0 * SRS + cgp * 4] = ra;   // cols>=29 -> pad
        if (r0 + 1 < XO) {
            float4 rb;
            rb.x = fmaxf(b0 * inv + beta, 0.f);
            rb.y = fmaxf(b1 * inv + beta, 0.f);
            rb.z = fmaxf(b2 * inv + beta, 0.f);
            rb.w = fmaxf(b3 * inv + beta, 0.f);
            *(float4*)&st[ch * SCST + (r0 + 1) * SRS + cgp * 4] = rb;
        }
    }
    __syncthreads();

    // ---- Phase C: xcorr, waves 0-1 = ch0, waves 2-3 = ch1; 125 lanes each
    {
        const int ch = tid >> 7;
        const int l  = tid & 127;
        if (l < 125) {
            const float* kb = &ktl[ch * 25];
            float kt[25];
            #pragma unroll
            for (int j = 0; j < 25; ++j) kt[j] = kb[j];
            int u  = l / 5;
            int v0 = (l - u * 5) * 5;
            const float* sbase = &st[ch * SCST + u * SRS + v0];
            float o0 = 0.f, o1 = 0.f, o2 = 0.f, o3 = 0.f, o4 = 0.f;
            #pragma unroll
            for (int p = 0; p < 5; ++p) {
                const float* rp = sbase + p * SRS;
                float r0 = rp[0], r1 = rp[1], r2 = rp[2], r3 = rp[3], r4 = rp[4],
                      r5 = rp[5], r6 = rp[6], r7 = rp[7], r8 = rp[8];
                float k0 = kt[p * 5], k1 = kt[p * 5 + 1], k2 = kt[p * 5 + 2],
                      k3 = kt[p * 5 + 3], k4 = kt[p * 5 + 4];
                o0 += r0 * k0 + r1 * k1 + r2 * k2 + r3 * k3 + r4 * k4;
                o1 += r1 * k0 + r2 * k1 + r3 * k2 + r4 * k3 + r5 * k4;
                o2 += r2 * k0 + r3 * k1 + r4 * k2 + r5 * k3 + r6 * k4;
                o3 += r3 * k0 + r4 * k1 + r5 * k2 + r6 * k3 + r7 * k4;
                o4 += r4 * k0 + r5 * k1 + r6 * k2 + r7 * k3 + r8 * k4;
            }
            unsigned short* op = out + ((size_t)zs * B_ * C_ + bc0 + ch) * OS2
                                     + u * OSP + v0;
            op[0] = f2bf(o0); op[1] = f2bf(o1); op[2] = f2bf(o2);
            op[3] = f2bf(o3); op[4] = f2bf(o4);
        }
    }
}

// frag load + MFMA macros for the persist-B GEMMs (3-deep kc pipeline)
#define LOADFR(D, KC, WAP, ROWB) do {                                          \
    _Pragma("unroll")                                                          \
    for (int mt_ = 0; mt_ < 4; ++mt_) {                                        \
        int row_ = (ROWB) + wm + mt_ * 16 + l16;                               \
        af[D][mt_] = *(const s16x8*)&(WAP)[(size_t)row_ * C_ + (KC) * 32 + quad * 8]; \
    }                                                                          \
    _Pragma("unroll")                                                          \
    for (int nt_ = 0; nt_ < 4; ++nt_)                                          \
        bf[D][nt_] = *(const s16x8*)&Bsh[(((KC) * 4 + quad) * 128 + wn + nt_ * 16 + l16) * 8]; \
} while (0)

#define MFMA16(D) do {                                                         \
    _Pragma("unroll")                                                          \
    for (int mt_ = 0; mt_ < 4; ++mt_)                                          \
        _Pragma("unroll")                                                      \
        for (int nt_ = 0; nt_ < 4; ++nt_)                                      \
            acc[mt_][nt_] = __builtin_amdgcn_mfma_f32_16x16x32_bf16(           \
                af[D][mt_], bf[D][nt_], acc[mt_][nt_], 0, 0, 0);               \
} while (0)

// ---------------------------------------------------------------------------
// Head GEMM v4 (persist-B + 3-deep kc prefetch).
// One block per (stage*b, s-tile): grid (5, 192). FULL B panel (64 KB) staged
// once -> ONE barrier; A streamed from global bf16 weights (L2-resident).
// v4: register ping-pong (depth 2) on af/bf across kc -> issue-to-use
// distance ~2x16 MFMA (~300 cyc w/ 2 waves/SIMD) covers L2 latency (~200).
// Regs ~190 (free: occupancy is LDS-capped at 2 blocks/CU).
// ---------------------------------------------------------------------------
__global__ __launch_bounds__(256) void c1_mfma(
    const unsigned short* __restrict__ X,
    const unsigned short* __restrict__ Wbf,
    const float* __restrict__ g, const float* __restrict__ bb,
    const float* __restrict__ mm, const float* __restrict__ vv,
    unsigned short* __restrict__ out)
{
    __shared__ unsigned short Bsh[32 * 128 * 8];   // 64 KB: [kq][col][k&7]
    __shared__ float s_inv[256], s_beta[256];

    const int tid  = threadIdx.x;
    const int wave = tid >> 6, lane = tid & 63;
    const int quad = lane >> 4, l16 = lane & 15;
    const int sb = blockIdx.x * 128;
    const int zs = blockIdx.y >> 6;        // stage
    const int b  = blockIdx.y & 63;
    const int wm = (wave & 1) * 64, wn = (wave >> 1) * 64;

    const float* gs  = g  + (size_t)zs * HD_;
    const float* bbs = bb + (size_t)zs * HD_;
    const float* mms = mm + (size_t)zs * HD_;
    const float* vvs = vv + (size_t)zs * HD_;
    const unsigned short* wA0 = Wbf + (size_t)zs * HD_ * C_;

    {
        float iv = gs[tid] * rsqrtf(vvs[tid] + EPSF);
        s_inv[tid]  = iv;
        s_beta[tid] = bbs[tid] - mms[tid] * iv;
    }

    const int sm = tid & 127;
    const int kh = tid >> 7;
    const unsigned short* Xb = X + ((size_t)zs * B_ + b) * C_ * OS2;
    const bool npred = (sb + sm) < OS2;

    #pragma unroll
    for (int kk = 0; kk < 8; ++kk) {
        unsigned short bu[16];
        #pragma unroll
        for (int j = 0; j < 16; ++j)
            bu[j] = npred ? Xb[(size_t)(kk * 32 + kh * 16 + j) * OS2 + sb + sm]
                          : (unsigned short)0;
        uint4 pb0, pb1;
        pb0.x = pk2(bu[0],  bu[1]);  pb0.y = pk2(bu[2],  bu[3]);
        pb0.z = pk2(bu[4],  bu[5]);  pb0.w = pk2(bu[6],  bu[7]);
        pb1.x = pk2(bu[8],  bu[9]);  pb1.y = pk2(bu[10], bu[11]);
        pb1.z = pk2(bu[12], bu[13]); pb1.w = pk2(bu[14], bu[15]);
        int kq0 = kk * 4 + kh * 2;
        *(uint4*)&Bsh[((kq0 + 0) * 128 + sm) * 8] = pb0;
        *(uint4*)&Bsh[((kq0 + 1) * 128 + sm) * 8] = pb1;
    }
    __syncthreads();

    #pragma unroll
    for (int mtile = 0; mtile < 2; ++mtile) {
        const int ob = mtile * 128;
        f32x4 acc[4][4];
        #pragma unroll
        for (int i = 0; i < 4; ++i)
            #pragma unroll
            for (int j = 0; j < 4; ++j)
                acc[i][j] = (f32x4){0.f, 0.f, 0.f, 0.f};

        s16x8 af[3][4], bf[3][4];
        LOADFR(0, 0, wA0, ob);
        LOADFR(1, 1, wA0, ob);
        #pragma unroll
        for (int kc = 0; kc < 8; ++kc) {
            if (kc < 6) LOADFR((kc + 2) % 3, kc + 2, wA0, ob);
            MFMA16(kc % 3);
        }

        #pragma unroll
        for (int mt = 0; mt < 4; ++mt) {
            #pragma unroll
            for (int r = 0; r < 4; ++r) {
                int orow = ob + wm + mt * 16 + quad * 4 + r;
                float iv = s_inv[orow], be = s_beta[orow];
                size_t obase = (((size_t)zs * B_ + b) * HD_ + orow) * OS2;
                #pragma unroll
                for (int nt = 0; nt < 4; ++nt) {
                    int s = sb + wn + nt * 16 + l16;
                    if (s < OS2)
                        out[obase + s] = f2bf(fmaxf(acc[mt][nt][r] * iv + be, 0.f));
                }
            }
        }
    }
}

// ---------------------------------------------------------------------------
// Fused 3-head GEMM v4 (persist-B + 3-deep kc prefetch) + w2 projection +
// weighted accumulate. grid (5, 192); B staged once, 6 M-tiles stream A.
// ---------------------------------------------------------------------------
__global__ __launch_bounds__(256) void heads3_mfma(
    const unsigned short* __restrict__ feat,
    const unsigned short* __restrict__ Wbf,
    const float* __restrict__ gc, const float* __restrict__ bc2, const float* __restrict__ mc, const float* __restrict__ vc,
    const float* __restrict__ gl, const float* __restrict__ bl, const float* __restrict__ ml, const float* __restrict__ vl,
    const float* __restrict__ gt, const float* __restrict__ bt, const float* __restrict__ mt2, const float* __restrict__ vt,
    const float* __restrict__ w2c, const float* __restrict__ w2l, const float* __restrict__ w2t,
    const float* __restrict__ wvc, const float* __restrict__ wvl, const float* __restrict__ wvt,
    float* __restrict__ oacc)
{
    __shared__ unsigned short Bsh[32 * 128 * 8];   // 64 KB: [kq][col][k&7]
    __shared__ float s_inv[3 * 256], s_beta[3 * 256];
    __shared__ float s_w2[7 * 256];                // cls 2x256 | loc 4x256 | ctr 256

    const int tid  = threadIdx.x;
    const int wave = tid >> 6, lane = tid & 63;
    const int quad = lane >> 4, l16 = lane & 15;
    const int sb = blockIdx.x * 128;
    const int zs = blockIdx.y >> 6;        // stage
    const int b  = blockIdx.y & 63;
    const int wm = (wave & 1) * 64, wn = (wave >> 1) * 64;

    // BN params for all 3 heads
    {
        float iv0 = gc[zs * HD_ + tid] * rsqrtf(vc[zs * HD_ + tid] + EPSF);
        s_inv[tid]        = iv0;
        s_beta[tid]       = bc2[zs * HD_ + tid] - mc[zs * HD_ + tid] * iv0;
        float iv1 = gl[zs * HD_ + tid] * rsqrtf(vl[zs * HD_ + tid] + EPSF);
        s_inv[256 + tid]  = iv1;
        s_beta[256 + tid] = bl[zs * HD_ + tid] - ml[zs * HD_ + tid] * iv1;
        float iv2 = gt[zs * HD_ + tid] * rsqrtf(vt[zs * HD_ + tid] + EPSF);
        s_inv[512 + tid]  = iv2;
        s_beta[512 + tid] = bt[zs * HD_ + tid] - mt2[zs * HD_ + tid] * iv2;
    }
    {
        s_w2[tid]       = w2c[zs * 512 + tid];
        s_w2[256 + tid] = w2c[zs * 512 + 256 + tid];
        #pragma unroll
        for (int q = 0; q < 4; ++q)
            s_w2[512 + q * 256 + tid] = w2l[zs * 1024 + q * 256 + tid];
        s_w2[1536 + tid] = w2t[zs * 256 + tid];
    }

    const int sm = tid & 127;
    const int kh = tid >> 7;
    const unsigned short* Xb = feat + ((size_t)zs * B_ + b) * C_ * OS2;
    const bool npred = (sb + sm) < OS2;

    #pragma unroll
    for (int kk = 0; kk < 8; ++kk) {
        unsigned short bu[16];
        #pragma unroll
        for (int j = 0; j < 16; ++j)
            bu[j] = npred ? Xb[(size_t)(kk * 32 + kh * 16 + j) * OS2 + sb + sm]
                          : (unsigned short)0;
        uint4 pb0, pb1;
        pb0.x = pk2(bu[0],  bu[1]);  pb0.y = pk2(bu[2],  bu[3]);
        pb0.z = pk2(bu[4],  bu[5]);  pb0.w = pk2(bu[6],  bu[7]);
        pb1.x = pk2(bu[8],  bu[9]);  pb1.y = pk2(bu[10], bu[11]);
        pb1.z = pk2(bu[12], bu[13]); pb1.w = pk2(bu[14], bu[15]);
        int kq0 = kk * 4 + kh * 2;
        *(uint4*)&Bsh[((kq0 + 0) * 128 + sm) * 8] = pb0;
        *(uint4*)&Bsh[((kq0 + 1) * 128 + sm) * 8] = pb1;
    }
    __syncthreads();

    // per-head softmax weights for this stage
    float wih[3];
    {
        float e0 = __expf(wvc[0]), e1 = __expf(wvc[1]), e2 = __expf(wvc[2]);
        wih[0] = ((zs == 0) ? e0 : (zs == 1) ? e1 : e2) / (e0 + e1 + e2);
        float f0 = __expf(wvl[0]), f1 = __expf(wvl[1]), f2 = __expf(wvl[2]);
        wih[1] = ((zs == 0) ? f0 : (zs == 1) ? f1 : f2) / (f0 + f1 + f2);
        float h0 = __expf(wvt[0]), h1 = __expf(wvt[1]), h2 = __expf(wvt[2]);
        wih[2] = ((zs == 0) ? h0 : (zs == 1) ? h1 : h2) / (h0 + h1 + h2);
    }

    for (int mtile = 0; mtile < 6; ++mtile) {
        const int head = mtile >> 1;
        const int lob  = (mtile & 1) * 128;
        const unsigned short* wA =
            Wbf + (size_t)(head + 1) * (3 * HD_ * C_) + (size_t)zs * HD_ * C_;

        f32x4 acc[4][4];
        #pragma unroll
        for (int i = 0; i < 4; ++i)
            #pragma unroll
            for (int j = 0; j < 4; ++j)
                acc[i][j] = (f32x4){0.f, 0.f, 0.f, 0.f};

        s16x8 af[3][4], bf[3][4];
        LOADFR(0, 0, wA, lob);
        LOADFR(1, 1, wA, lob);
        #pragma unroll
        for (int kc = 0; kc < 8; ++kc) {
            if (kc < 6) LOADFR((kc + 2) % 3, kc + 2, wA, lob);
            MFMA16(kc % 3);
        }

        // BN+ReLU in place
        #pragma unroll
        for (int mt = 0; mt < 4; ++mt)
            #pragma unroll
            for (int r = 0; r < 4; ++r) {
                int orow = lob + wm + mt * 16 + quad * 4 + r;
                float iv = s_inv[head * 256 + orow];
                float be = s_beta[head * 256 + orow];
                #pragma unroll
                for (int nt = 0; nt < 4; ++nt)
                    acc[mt][nt][r] = fmaxf(acc[mt][nt][r] * iv + be, 0.f);
            }

        const int CON   = (head == 0) ? 2 : (head == 1) ? 4 : 1;
        const int w2off = (head == 0) ? 0 : (head == 1) ? 512 : 1536;
        const float wi  = wih[head];

        float* obase;
        if (head == 0)      obase = oacc + (size_t)b * 2 * OS2;
        else if (head == 1) obase = oacc + (size_t)B_ * 2 * OS2 + (size_t)b * 4 * OS2;
        else                obase = oacc + (size_t)B_ * 6 * OS2 + (size_t)b * OS2;

        for (int co = 0; co < CON; ++co) {
            float red[4] = {0.f, 0.f, 0.f, 0.f};
            #pragma unroll
            for (int mt = 0; mt < 4; ++mt)
                #pragma unroll
                for (int r = 0; r < 4; ++r) {
                    float w2v = s_w2[w2off + co * 256 + lob + wm + mt * 16 + quad * 4 + r];
                    #pragma unroll
                    for (int nt = 0; nt < 4; ++nt)
                        red[nt] += w2v * acc[mt][nt][r];
                }
            #pragma unroll
            for (int nt = 0; nt < 4; ++nt) {
                red[nt] += __shfl_xor(red[nt], 16);
                red[nt] += __shfl_xor(red[nt], 32);
            }
            if (quad == 0) {
                #pragma unroll
                for (int nt = 0; nt < 4; ++nt) {
                    int s = sb + wn + nt * 16 + l16;
                    if (s < OS2)
                        atomicAdd(obase + (size_t)co * OS2 + s, wi * red[nt]);
                }
            }
        }
    }
}

// ---------------------------------------------------------------------------
// Final bias add: out += sum_i softmax(w)[i] * b2[i][co], in place on d_out.
// ---------------------------------------------------------------------------
__global__ void bias_out(float* __restrict__ out,
    const float* __restrict__ cb2, const float* __restrict__ lb2,
    const float* __restrict__ tb2, const float* __restrict__ wvc,
    const float* __restrict__ wvl, const float* __restrict__ wvt)
{
    int n = blockIdx.x * 256 + threadIdx.x;
    if (n >= B_ * 7 * OS2) return;
    float bias;
    if (n < B_ * 2 * OS2) {
        float e0 = __expf(wvc[0]), e1 = __expf(wvc[1]), e2 = __expf(wvc[2]);
        int co = (n / OS2) & 1;
        bias = (e0 * cb2[co] + e1 * cb2[2 + co] + e2 * cb2[4 + co]) / (e0 + e1 + e2);
    } else if (n < B_ * 6 * OS2) {
        float e0 = __expf(wvl[0]), e1 = __expf(wvl[1]), e2 = __expf(wvl[2]);
        int co = ((n - B_ * 2 * OS2) / OS2) & 3;
        bias = (e0 * lb2[co] + e1 * lb2[4 + co] + e2 * lb2[8 + co]) / (e0 + e1 + e2);
    } else {
        float e0 = __expf(wvt[0]), e1 = __expf(wvt[1]), e2 = __expf(wvt[2]);
        bias = (e0 * tb2[0] + e1 * tb2[1] + e2 * tb2[2]) / (e0 + e1 + e2);
    }
    out[n] += bias;
}

__global__ void fillf_k(float* __restrict__ out, int n, float v)
{
    int i = blockIdx.x * 256 + threadIdx.x;
    if (i < n) out[i] = v;
}

// ===========================================================================
extern "C" void kernel_launch(void* const* d_in, const int* in_sizes, int n_in,
                              void* d_out, int out_size, void* d_ws, size_t ws_size,
                              hipStream_t stream)
{
    static const int EXP_SIZES[36] = {
        2408448, 47235072, 6912,
        768, 768, 768, 768,
        196608, 768, 768, 768, 768,
        196608, 768, 768, 768, 768, 1536, 6,
        196608, 768, 768, 768, 768, 3072, 12,
        196608, 768, 768, 768, 768, 768, 3,
        3, 3, 3
    };
    const int OUT_N = B_ * 7 * OS2;                  // 280,000
    const size_t stageEl = (size_t)B_ * C_ * OS2;    // 10,240,000 elems (bf16)
    const size_t WBF_EL  = (size_t)4 * 3 * HD_ * C_; // 786,432
    const size_t NEED_WS = (6 * stageEl + WBF_EL) * sizeof(unsigned short);

    int bad = -1;
    if (n_in != 36) bad = 99;
    else {
        for (int i = 0; i < 36; ++i)
            if (in_sizes[i] != EXP_SIZES[i]) { bad = i; break; }
    }
    if (bad < 0 && ws_size < NEED_WS) bad = 90;      // 124.5 MB (proved present)
    if (bad < 0 && out_size != 280000) bad = 95;
    if (bad >= 0) {
        fillf_k<<<(out_size + 255) / 256, 256, 0, stream>>>(
            (float*)d_out, out_size, 500.f + 4.f * bad);
        return;
    }

    const float* z_fs   = (const float*)d_in[0];
    const float* x_fs   = (const float*)d_in[1];
    const float* pre_w  = (const float*)d_in[2];
    const float* pre_g  = (const float*)d_in[3];
    const float* pre_b  = (const float*)d_in[4];
    const float* pre_m  = (const float*)d_in[5];
    const float* pre_v  = (const float*)d_in[6];
    const float* head_w = (const float*)d_in[7];
    const float* head_g = (const float*)d_in[8];
    const float* head_b = (const float*)d_in[9];
    const float* head_m = (const float*)d_in[10];
    const float* head_v = (const float*)d_in[11];
    const float* cls_w1 = (const float*)d_in[12];
    const float* cls_g  = (const float*)d_in[13];
    const float* cls_b  = (const float*)d_in[14];
    const float* cls_m  = (const float*)d_in[15];
    const float* cls_v  = (const float*)d_in[16];
    const float* cls_w2 = (const float*)d_in[17];
    const float* cls_b2 = (const float*)d_in[18];
    const float* loc_w1 = (const float*)d_in[19];
    const float* loc_g  = (const float*)d_in[20];
    const float* loc_b  = (const float*)d_in[21];
    const float* loc_m  = (const float*)d_in[22];
    const float* loc_v  = (const float*)d_in[23];
    const float* loc_w2 = (const float*)d_in[24];
    const float* loc_b2 = (const float*)d_in[25];
    const float* ctr_w1 = (const float*)d_in[26];
    const float* ctr_g  = (const float*)d_in[27];
    const float* ctr_b  = (const float*)d_in[28];
    const float* ctr_m  = (const float*)d_in[29];
    const float* ctr_v  = (const float*)d_in[30];
    const float* ctr_w2 = (const float*)d_in[31];
    const float* ctr_b2 = (const float*)d_in[32];
    const float* w_cls  = (const float*)d_in[33];
    const float* w_loc  = (const float*)d_in[34];
    const float* w_ctr  = (const float*)d_in[35];

    unsigned short* xc   = (unsigned short*)d_ws;
    unsigned short* feat = xc + 3 * stageEl;
    unsigned short* wbf  = feat + 3 * stageEl;

    hipMemsetAsync(d_out, 0, (size_t)OUT_N * sizeof(float), stream);

    wconv_k<<<(4 * 196608 + 255) / 256, 256, 0, stream>>>(
        head_w, cls_w1, loc_w1, ctr_w1, wbf);

    fused_pre_xcorr<<<dim3(B_ * C_ / 2, 3), 256, 0, stream>>>(
        x_fs, z_fs, pre_w, pre_g, pre_b, pre_m, pre_v, xc, 0);

    c1_mfma<<<dim3(5, 3 * B_), 256, 0, stream>>>(
        xc, wbf, head_g, head_b, head_m, head_v, feat);

    heads3_mfma<<<dim3(5, 3 * B_), 256, 0, stream>>>(
        feat, wbf,
        cls_g, cls_b, cls_m, cls_v,
        loc_g, loc_b, loc_m, loc_v,
        ctr_g, ctr_b, ctr_m, ctr_v,
        cls_w2, loc_w2, ctr_w2,
        w_cls, w_loc, w_ctr, (float*)d_out);

    bias_out<<<(OUT_N + 255) / 256, 256, 0, stream>>>(
        (float*)d_out, cls_b2, loc_b2, ctr_b2, w_cls, w_loc, w_ctr);
}

// Round 5
// 546.614 us; speedup vs baseline: 1.1121x; 1.1121x over previous
//
#include <hip/hip_runtime.h>
#include <hip/hip_bf16.h>

using bf16 = __hip_bfloat16;

#define B_  64
#define C_  256
#define HD_ 256
#define XS  31
#define XO  29
#define ZS  7
#define ZO  5
#define OSP 25
#define XO2 (XO*XO)    // 841
#define ZO2 (ZO*ZO)    // 25
#define OS2 (OSP*OSP)  // 625
#define EPSF 1e-5f

// LDS strides for fused_pre (v4)
#define XCST 976          // per-channel stride in xt (961 used, 16B-aligned)
#define SRS  36           // st row stride (floats)
#define SCST (29 * SRS)   // 1044 per-channel st stride

typedef __attribute__((ext_vector_type(4))) float f32x4;
typedef __attribute__((ext_vector_type(8))) short s16x8;

__device__ __forceinline__ unsigned short f2bf(float f) {
    union { float f; unsigned int u; } a; a.f = f;
    unsigned int r = a.u + 0x7FFF + ((a.u >> 16) & 1);   // RNE
    return (unsigned short)(r >> 16);
}
__device__ __forceinline__ unsigned int pk2(unsigned short a, unsigned short b) {
    return (unsigned int)a | ((unsigned int)b << 16);
}

// ---------------------------------------------------------------------------
// One-time fp32->bf16 conversion of all GEMM weights into workspace.
// Layout: [head_w 3*65536 | cls_w1 3*65536 | loc_w1 3*65536 | ctr_w1 3*65536]
// ---------------------------------------------------------------------------
__global__ void wconv_k(const float* __restrict__ hw, const float* __restrict__ cw,
                        const float* __restrict__ lw, const float* __restrict__ tw,
                        unsigned short* __restrict__ o)
{
    int i = blockIdx.x * 256 + threadIdx.x;
    if (i >= 4 * 196608) return;
    int seg = i / 196608, r = i - seg * 196608;
    const float* s = (seg == 0) ? hw : (seg == 1) ? cw : (seg == 2) ? lw : tw;
    o[i] = f2bf(s[r]);
}

// ---------------------------------------------------------------------------
// Fused: dw3+BN+ReLU on x-tile and z-tile, then depthwise 5x5 xcorr.
// v4: TWO (b,c) pairs per block (grid x = B*C/2).
// ---------------------------------------------------------------------------
__global__ __launch_bounds__(256) void fused_pre_xcorr(
    const float* __restrict__ x, const float* __restrict__ z,
    const float* __restrict__ w, const float* __restrict__ g,
    const float* __restrict__ bb, const float* __restrict__ mm,
    const float* __restrict__ vv, unsigned short* __restrict__ out,
    int si_base)
{
    const int zs  = blockIdx.y;            // local stage (output buffer)
    const int si  = si_base + zs;          // global stage (inputs)
    const int bc0 = blockIdx.x * 2;        // first of 2 (b,c); same b, c even
    const int tid = threadIdx.x;

    __shared__ float xt[2 * XCST + 8];     // x tiles, linear rows (stride 31)
    __shared__ float st[2 * SCST + 16];    // dw3 features, row stride 36
    __shared__ float zt[2 * 49];
    __shared__ float ktl[2 * 25];
    __shared__ float wtl[2 * 9];
    __shared__ float sprm[4];              // inv0, beta0, inv1, beta1

    // ---- Phase A: coalesced load of both x tiles (1922 consecutive floats)
    const float* xp = x + ((size_t)si * B_ * C_ + bc0) * (XS * XS);
    #pragma unroll
    for (int k2 = 0; k2 < 8; ++k2) {
        int idx = tid + k2 * 256;
        if (idx < 2 * XS * XS) {
            int off = idx + (idx >= XS * XS ? (XCST - XS * XS) : 0);
            xt[off] = xp[idx];
        }
    }
    if (tid < 98) zt[tid] = z[((size_t)si * B_ * C_ + bc0) * 49 + tid];
    if (tid < 18) wtl[tid] = w[((size_t)si * C_ + (bc0 & (C_ - 1))) * 9 + tid];
    if (tid < 2) {
        int cg = si * C_ + (bc0 & (C_ - 1)) + tid;
        float iv = g[cg] * rsqrtf(vv[cg] + EPSF);
        sprm[tid * 2]     = iv;
        sprm[tid * 2 + 1] = bb[cg] - mm[cg] * iv;
    }
    __syncthreads();

    // ---- kernel features (two 5x5 tiles), threads 0..49
    if (tid < 50) {
        int ch = (tid >= 25) ? 1 : 0;
        int l  = tid - ch * 25;
        int oy = l / 5, ox = l - (l / 5) * 5;
        const float* zb = &zt[ch * 49];
        const float* wb = &wtl[ch * 9];
        float a = 0.f;
        #pragma unroll
        for (int dy = 0; dy < 3; ++dy)
            #pragma unroll
            for (int dx = 0; dx < 3; ++dx)
                a += zb[(oy + dy) * ZS + ox + dx] * wb[dy * 3 + dx];
        ktl[ch * 25 + l] = fmaxf(a * sprm[ch * 2] + sprm[ch * 2 + 1], 0.f);
    }

    // ---- Phase B: search features, 2-row x 4-col strips, threads 0..239
    if (tid < 240) {
        int ch    = (tid >= 120) ? 1 : 0;
        int rem   = tid - ch * 120;
        int strip = rem >> 3;              // 0..14  (rows 2s, 2s+1)
        int cgp   = rem & 7;               // 0..7   (cols 4cg..4cg+3)
        int r0    = strip * 2;
        const float* base = &xt[ch * XCST + r0 * XS + cgp * 4];
        const float* wb   = &wtl[ch * 9];
        float w0 = wb[0], w1 = wb[1], w2 = wb[2],
              w3 = wb[3], w4 = wb[4], w5 = wb[5],
              w6 = wb[6], w7 = wb[7], w8 = wb[8];
        const float inv  = sprm[ch * 2];
        const float beta = sprm[ch * 2 + 1];

        float a0 = 0.f, a1 = 0.f, a2 = 0.f, a3 = 0.f;   // row r0
        float b0 = 0.f, b1 = 0.f, b2 = 0.f, b3 = 0.f;   // row r0+1
        #pragma unroll
        for (int dy = 0; dy < 4; ++dy) {
            const float* rp = base + dy * XS;
            float v0 = rp[0], v1 = rp[1], v2 = rp[2],
                  v3 = rp[3], v4 = rp[4], v5 = rp[5];
            if (dy < 3) {
                float u0 = (dy == 0) ? w0 : (dy == 1) ? w3 : w6;
                float u1 = (dy == 0) ? w1 : (dy == 1) ? w4 : w7;
                float u2 = (dy == 0) ? w2 : (dy == 1) ? w5 : w8;
                a0 += v0 * u0 + v1 * u1 + v2 * u2;
                a1 += v1 * u0 + v2 * u1 + v3 * u2;
                a2 += v2 * u0 + v3 * u1 + v4 * u2;
                a3 += v3 * u0 + v4 * u1 + v5 * u2;
            }
            if (dy >= 1) {
                float u0 = (dy == 1) ? w0 : (dy == 2) ? w3 : w6;
                float u1 = (dy == 1) ? w1 : (dy == 2) ? w4 : w7;
                float u2 = (dy == 1) ? w2 : (dy == 2) ? w5 : w8;
                b0 += v0 * u0 + v1 * u1 + v2 * u2;
                b1 += v1 * u0 + v2 * u1 + v3 * u2;
                b2 += v2 * u0 + v3 * u1 + v4 * u2;
                b3 += v3 * u0 + v4 * u1 + v5 * u2;
            }
        }
        float4 ra;
        ra.x = fmaxf(a0 * inv + beta, 0.f);
        ra.y = fmaxf(a1 * inv + beta, 0.f);
        ra.z = fmaxf(a2 * inv + beta, 0.f);
        ra.w = fmaxf(a3 * inv + beta, 0.f);
        *(float4*)&st[ch * SCST + r0 * SRS + cgp * 4] = ra;   // cols>=29 -> pad
        if (r0 + 1 < XO) {
            float4 rb;
            rb.x = fmaxf(b0 * inv + beta, 0.f);
            rb.y = fmaxf(b1 * inv + beta, 0.f);
            rb.z = fmaxf(b2 * inv + beta, 0.f);
            rb.w = fmaxf(b3 * inv + beta, 0.f);
            *(float4*)&st[ch * SCST + (r0 + 1) * SRS + cgp * 4] = rb;
        }
    }
    __syncthreads();

    // ---- Phase C: xcorr, waves 0-1 = ch0, waves 2-3 = ch1; 125 lanes each
    {
        const int ch = tid >> 7;
        const int l  = tid & 127;
        if (l < 125) {
            const float* kb = &ktl[ch * 25];
            float kt[25];
            #pragma unroll
            for (int j = 0; j < 25; ++j) kt[j] = kb[j];
            int u  = l / 5;
            int v0 = (l - u * 5) * 5;
            const float* sbase = &st[ch * SCST + u * SRS + v0];
            float o0 = 0.f, o1 = 0.f, o2 = 0.f, o3 = 0.f, o4 = 0.f;
            #pragma unroll
            for (int p = 0; p < 5; ++p) {
                const float* rp = sbase + p * SRS;
                float r0 = rp[0], r1 = rp[1], r2 = rp[2], r3 = rp[3], r4 = rp[4],
                      r5 = rp[5], r6 = rp[6], r7 = rp[7], r8 = rp[8];
                float k0 = kt[p * 5], k1 = kt[p * 5 + 1], k2 = kt[p * 5 + 2],
                      k3 = kt[p * 5 + 3], k4 = kt[p * 5 + 4];
                o0 += r0 * k0 + r1 * k1 + r2 * k2 + r3 * k3 + r4 * k4;
                o1 += r1 * k0 + r2 * k1 + r3 * k2 + r4 * k3 + r5 * k4;
                o2 += r2 * k0 + r3 * k1 + r4 * k2 + r5 * k3 + r6 * k4;
                o3 += r3 * k0 + r4 * k1 + r5 * k2 + r6 * k3 + r7 * k4;
                o4 += r4 * k0 + r5 * k1 + r6 * k2 + r7 * k3 + r8 * k4;
            }
            unsigned short* op = out + ((size_t)zs * B_ * C_ + bc0 + ch) * OS2
                                     + u * OSP + v0;
            op[0] = f2bf(o0); op[1] = f2bf(o1); op[2] = f2bf(o2);
            op[3] = f2bf(o3); op[4] = f2bf(o4);
        }
    }
}

// ---------------------------------------------------------------------------
// Head GEMM (round-2 structure + XCD-group swizzle).
// 1-D grid 1920: lid = (t&7) + 8*(mtile + 2*(t>>3)), t = x + 5*z (s-tile,
// stage*b). Both mtile blocks of a t share lid%8 -> same XCD -> B panel is
// fetched from HBM once, hit in that XCD's L2 by the sibling.
// Block tile 128x128, K-chunks of 32, 4 waves, 16x16x32 MFMA.
// ---------------------------------------------------------------------------
__global__ __launch_bounds__(256) void c1_mfma(
    const unsigned short* __restrict__ X,
    const unsigned short* __restrict__ Wbf,
    const float* __restrict__ g, const float* __restrict__ bb,
    const float* __restrict__ mm, const float* __restrict__ vv,
    unsigned short* __restrict__ out)
{
    __shared__ unsigned short Abuf[4 * 128 * 8];
    __shared__ unsigned short Bbuf[4 * 128 * 8];
    __shared__ float s_inv[128], s_beta[128];

    const int lid = blockIdx.x;
    const int k8  = lid & 7;
    const int r   = lid >> 3;
    const int mt6 = r & 1;                 // ob half
    const int j   = r >> 1;
    const int t   = k8 + 8 * j;            // 0..959
    const int sx  = t % 5;
    const int zb  = t / 5;                 // 0..191 = stage*64+b

    const int tid  = threadIdx.x;
    const int wave = tid >> 6, lane = tid & 63;
    const int quad = lane >> 4, l16 = lane & 15;
    const int sb = sx * 128;
    const int ob = mt6 * 128;
    const int zs = zb >> 6;
    const int b  = zb & 63;
    const int wm = (wave & 1) * 64, wn = (wave >> 1) * 64;

    const float* gs  = g  + (size_t)zs * HD_;
    const float* bbs = bb + (size_t)zs * HD_;
    const float* mms = mm + (size_t)zs * HD_;
    const float* vvs = vv + (size_t)zs * HD_;
    const unsigned short* Wbs = Wbf + (size_t)zs * HD_ * C_;

    if (tid < 128) {
        int o = ob + tid;
        float iv = gs[o] * rsqrtf(vvs[o] + EPSF);
        s_inv[tid]  = iv;
        s_beta[tid] = bbs[o] - mms[o] * iv;
    }

    const int sm = tid & 127;
    const int kh = tid >> 7;
    const unsigned short* Xb = X + ((size_t)zs * B_ + b) * C_ * OS2;
    const bool npred = (sb + sm) < OS2;

    f32x4 acc[4][4];
    #pragma unroll
    for (int i = 0; i < 4; ++i)
        #pragma unroll
        for (int jj = 0; jj < 4; ++jj)
            acc[i][jj] = (f32x4){0.f, 0.f, 0.f, 0.f};

    for (int kk = 0; kk < C_; kk += 32) {
        const unsigned short* wp = Wbs + (size_t)(ob + sm) * C_ + kk + kh * 16;
        uint4 pa0 = *(const uint4*)(wp);
        uint4 pa1 = *(const uint4*)(wp + 8);
        *(uint4*)&Abuf[((kh * 2 + 0) * 128 + sm) * 8] = pa0;
        *(uint4*)&Abuf[((kh * 2 + 1) * 128 + sm) * 8] = pa1;

        unsigned short bu[16];
        #pragma unroll
        for (int jj = 0; jj < 16; ++jj)
            bu[jj] = npred ? Xb[(size_t)(kk + kh * 16 + jj) * OS2 + sb + sm]
                           : (unsigned short)0;
        uint4 pb0, pb1;
        pb0.x = pk2(bu[0],  bu[1]);  pb0.y = pk2(bu[2],  bu[3]);
        pb0.z = pk2(bu[4],  bu[5]);  pb0.w = pk2(bu[6],  bu[7]);
        pb1.x = pk2(bu[8],  bu[9]);  pb1.y = pk2(bu[10], bu[11]);
        pb1.z = pk2(bu[12], bu[13]); pb1.w = pk2(bu[14], bu[15]);
        *(uint4*)&Bbuf[((kh * 2 + 0) * 128 + sm) * 8] = pb0;
        *(uint4*)&Bbuf[((kh * 2 + 1) * 128 + sm) * 8] = pb1;

        __syncthreads();

        s16x8 af[4], bfr[4];
        #pragma unroll
        for (int mt = 0; mt < 4; ++mt)
            af[mt] = *(const s16x8*)&Abuf[(quad * 128 + wm + mt * 16 + l16) * 8];
        #pragma unroll
        for (int nt = 0; nt < 4; ++nt)
            bfr[nt] = *(const s16x8*)&Bbuf[(quad * 128 + wn + nt * 16 + l16) * 8];
        #pragma unroll
        for (int mt = 0; mt < 4; ++mt)
            #pragma unroll
            for (int nt = 0; nt < 4; ++nt)
                acc[mt][nt] = __builtin_amdgcn_mfma_f32_16x16x32_bf16(
                    af[mt], bfr[nt], acc[mt][nt], 0, 0, 0);

        __syncthreads();
    }

    #pragma unroll
    for (int mt = 0; mt < 4; ++mt) {
        #pragma unroll
        for (int rr = 0; rr < 4; ++rr) {
            int orow = wm + mt * 16 + quad * 4 + rr;
            float iv = s_inv[orow], be = s_beta[orow];
            size_t obase = (((size_t)zs * B_ + b) * HD_ + (ob + orow)) * OS2;
            #pragma unroll
            for (int nt = 0; nt < 4; ++nt) {
                int s = sb + wn + nt * 16 + l16;
                if (s < OS2)
                    out[obase + s] = f2bf(fmaxf(acc[mt][nt][rr] * iv + be, 0.f));
            }
        }
    }
}

// ---------------------------------------------------------------------------
// Fused 3-head hidden GEMM + w2 projection + softmax-weighted accumulate
// (round-2 structure + XCD-group swizzle).
// 1-D grid 5760: lid = (t&7) + 8*(mtile + 6*(t>>3)), t = x + 5*z.
// All 6 mtile blocks (cls/cls/loc/loc/ctr/ctr) of a t share lid%8 -> same
// XCD -> the 64 KB feat B-panel is HBM-fetched once, 5 L2 hits.
// ---------------------------------------------------------------------------
__global__ __launch_bounds__(256) void heads3_mfma(
    const unsigned short* __restrict__ feat,
    const unsigned short* __restrict__ Wbf,
    const float* __restrict__ gc, const float* __restrict__ bc2, const float* __restrict__ mc, const float* __restrict__ vc,
    const float* __restrict__ gl, const float* __restrict__ bl, const float* __restrict__ ml, const float* __restrict__ vl,
    const float* __restrict__ gt, const float* __restrict__ bt, const float* __restrict__ mt2, const float* __restrict__ vt,
    const float* __restrict__ w2c, const float* __restrict__ w2l, const float* __restrict__ w2t,
    const float* __restrict__ wvc, const float* __restrict__ wvl, const float* __restrict__ wvt,
    float* __restrict__ oacc)
{
    __shared__ unsigned short Abuf[4 * 128 * 8];
    __shared__ unsigned short Bbuf[4 * 128 * 8];
    __shared__ float s_inv[128], s_beta[128];
    __shared__ float s_w2[4 * 256];

    const int lid = blockIdx.x;
    const int k8  = lid & 7;
    const int r   = lid >> 3;
    const int by  = r % 6;                 // mtile: head*2 + half
    const int j   = r / 6;
    const int t   = k8 + 8 * j;            // 0..959
    const int sx  = t % 5;
    const int zb  = t / 5;

    const int tid  = threadIdx.x;
    const int wave = tid >> 6, lane = tid & 63;
    const int quad = lane >> 4, l16 = lane & 15;
    const int sb   = sx * 128;
    const int head = by >> 1;
    const int lob  = (by & 1) * 128;
    const int zs   = zb >> 6;
    const int b    = zb & 63;
    const int wm = (wave & 1) * 64, wn = (wave >> 1) * 64;

    const float* g  = (head == 0) ? gc  : (head == 1) ? gl  : gt;
    const float* bb = (head == 0) ? bc2 : (head == 1) ? bl  : bt;
    const float* mm = (head == 0) ? mc  : (head == 1) ? ml  : mt2;
    const float* vv = (head == 0) ? vc  : (head == 1) ? vl  : vt;
    const float* w2 = (head == 0) ? w2c : (head == 1) ? w2l : w2t;
    const float* wv = (head == 0) ? wvc : (head == 1) ? wvl : wvt;
    const int  CON  = (head == 0) ? 2 : (head == 1) ? 4 : 1;

    const unsigned short* Wbs =
        Wbf + (size_t)(head + 1) * (3 * HD_ * C_) + (size_t)zs * HD_ * C_;
    g  += (size_t)zs * HD_;  bb += (size_t)zs * HD_;
    mm += (size_t)zs * HD_;  vv += (size_t)zs * HD_;
    w2 += (size_t)zs * CON * HD_;

    if (tid < 128) {
        int o = lob + tid;
        float iv = g[o] * rsqrtf(vv[o] + EPSF);
        s_inv[tid]  = iv;
        s_beta[tid] = bb[o] - mm[o] * iv;
    }
    for (int tt = tid; tt < CON * 256; tt += 256) s_w2[tt] = w2[tt];

    const int sm = tid & 127;
    const int kh = tid >> 7;
    const unsigned short* Xb = feat + ((size_t)zs * B_ + b) * C_ * OS2;
    const bool npred = (sb + sm) < OS2;

    f32x4 acc[4][4];
    #pragma unroll
    for (int i = 0; i < 4; ++i)
        #pragma unroll
        for (int jj = 0; jj < 4; ++jj)
            acc[i][jj] = (f32x4){0.f, 0.f, 0.f, 0.f};

    for (int kk = 0; kk < C_; kk += 32) {
        const unsigned short* wp = Wbs + (size_t)(lob + sm) * C_ + kk + kh * 16;
        uint4 pa0 = *(const uint4*)(wp);
        uint4 pa1 = *(const uint4*)(wp + 8);
        *(uint4*)&Abuf[((kh * 2 + 0) * 128 + sm) * 8] = pa0;
        *(uint4*)&Abuf[((kh * 2 + 1) * 128 + sm) * 8] = pa1;

        unsigned short bu[16];
        #pragma unroll
        for (int jj = 0; jj < 16; ++jj)
            bu[jj] = npred ? Xb[(size_t)(kk + kh * 16 + jj) * OS2 + sb + sm]
                           : (unsigned short)0;
        uint4 pb0, pb1;
        pb0.x = pk2(bu[0],  bu[1]);  pb0.y = pk2(bu[2],  bu[3]);
        pb0.z = pk2(bu[4],  bu[5]);  pb0.w = pk2(bu[6],  bu[7]);
        pb1.x = pk2(bu[8],  bu[9]);  pb1.y = pk2(bu[10], bu[11]);
        pb1.z = pk2(bu[12], bu[13]); pb1.w = pk2(bu[14], bu[15]);
        *(uint4*)&Bbuf[((kh * 2 + 0) * 128 + sm) * 8] = pb0;
        *(uint4*)&Bbuf[((kh * 2 + 1) * 128 + sm) * 8] = pb1;

        __syncthreads();

        s16x8 af[4], bfr[4];
        #pragma unroll
        for (int mt = 0; mt < 4; ++mt)
            af[mt] = *(const s16x8*)&Abuf[(quad * 128 + wm + mt * 16 + l16) * 8];
        #pragma unroll
        for (int nt = 0; nt < 4; ++nt)
            bfr[nt] = *(const s16x8*)&Bbuf[(quad * 128 + wn + nt * 16 + l16) * 8];
        #pragma unroll
        for (int mt = 0; mt < 4; ++mt)
            #pragma unroll
            for (int nt = 0; nt < 4; ++nt)
                acc[mt][nt] = __builtin_amdgcn_mfma_f32_16x16x32_bf16(
                    af[mt], bfr[nt], acc[mt][nt], 0, 0, 0);

        __syncthreads();
    }

    // BN+ReLU in place
    #pragma unroll
    for (int mt = 0; mt < 4; ++mt)
        #pragma unroll
        for (int rr = 0; rr < 4; ++rr) {
            int orow = wm + mt * 16 + quad * 4 + rr;
            float iv = s_inv[orow], be = s_beta[orow];
            #pragma unroll
            for (int nt = 0; nt < 4; ++nt)
                acc[mt][nt][rr] = fmaxf(acc[mt][nt][rr] * iv + be, 0.f);
        }

    const float e0 = __expf(wv[0]), e1 = __expf(wv[1]), e2 = __expf(wv[2]);
    const float wi = ((zs == 0) ? e0 : (zs == 1) ? e1 : e2) / (e0 + e1 + e2);

    float* obase;
    if (head == 0)      obase = oacc + (size_t)b * 2 * OS2;
    else if (head == 1) obase = oacc + (size_t)B_ * 2 * OS2 + (size_t)b * 4 * OS2;
    else                obase = oacc + (size_t)B_ * 6 * OS2 + (size_t)b * OS2;

    for (int co = 0; co < CON; ++co) {
        float red[4] = {0.f, 0.f, 0.f, 0.f};
        #pragma unroll
        for (int mt = 0; mt < 4; ++mt)
            #pragma unroll
            for (int rr = 0; rr < 4; ++rr) {
                float w2v = s_w2[co * 256 + lob + wm + mt * 16 + quad * 4 + rr];
                #pragma unroll
                for (int nt = 0; nt < 4; ++nt)
                    red[nt] += w2v * acc[mt][nt][rr];
            }
        #pragma unroll
        for (int nt = 0; nt < 4; ++nt) {
            red[nt] += __shfl_xor(red[nt], 16);
            red[nt] += __shfl_xor(red[nt], 32);
        }
        if (quad == 0) {
            #pragma unroll
            for (int nt = 0; nt < 4; ++nt) {
                int s = sb + wn + nt * 16 + l16;
                if (s < OS2)
                    atomicAdd(obase + (size_t)co * OS2 + s, wi * red[nt]);
            }
        }
    }
}

// ---------------------------------------------------------------------------
// Final bias add: out += sum_i softmax(w)[i] * b2[i][co], in place on d_out.
// ---------------------------------------------------------------------------
__global__ void bias_out(float* __restrict__ out,
    const float* __restrict__ cb2, const float* __restrict__ lb2,
    const float* __restrict__ tb2, const float* __restrict__ wvc,
    const float* __restrict__ wvl, const float* __restrict__ wvt)
{
    int n = blockIdx.x * 256 + threadIdx.x;
    if (n >= B_ * 7 * OS2) return;
    float bias;
    if (n < B_ * 2 * OS2) {
        float e0 = __expf(wvc[0]), e1 = __expf(wvc[1]), e2 = __expf(wvc[2]);
        int co = (n / OS2) & 1;
        bias = (e0 * cb2[co] + e1 * cb2[2 + co] + e2 * cb2[4 + co]) / (e0 + e1 + e2);
    } else if (n < B_ * 6 * OS2) {
        float e0 = __expf(wvl[0]), e1 = __expf(wvl[1]), e2 = __expf(wvl[2]);
        int co = ((n - B_ * 2 * OS2) / OS2) & 3;
        bias = (e0 * lb2[co] + e1 * lb2[4 + co] + e2 * lb2[8 + co]) / (e0 + e1 + e2);
    } else {
        float e0 = __expf(wvt[0]), e1 = __expf(wvt[1]), e2 = __expf(wvt[2]);
        bias = (e0 * tb2[0] + e1 * tb2[1] + e2 * tb2[2]) / (e0 + e1 + e2);
    }
    out[n] += bias;
}

__global__ void fillf_k(float* __restrict__ out, int n, float v)
{
    int i = blockIdx.x * 256 + threadIdx.x;
    if (i < n) out[i] = v;
}

// ===========================================================================
extern "C" void kernel_launch(void* const* d_in, const int* in_sizes, int n_in,
                              void* d_out, int out_size, void* d_ws, size_t ws_size,
                              hipStream_t stream)
{
    static const int EXP_SIZES[36] = {
        2408448, 47235072, 6912,
        768, 768, 768, 768,
        196608, 768, 768, 768, 768,
        196608, 768, 768, 768, 768, 1536, 6,
        196608, 768, 768, 768, 768, 3072, 12,
        196608, 768, 768, 768, 768, 768, 3,
        3, 3, 3
    };
    const int OUT_N = B_ * 7 * OS2;                  // 280,000
    const size_t stageEl = (size_t)B_ * C_ * OS2;    // 10,240,000 elems (bf16)
    const size_t WBF_EL  = (size_t)4 * 3 * HD_ * C_; // 786,432
    const size_t NEED_WS = (6 * stageEl + WBF_EL) * sizeof(unsigned short);

    int bad = -1;
    if (n_in != 36) bad = 99;
    else {
        for (int i = 0; i < 36; ++i)
            if (in_sizes[i] != EXP_SIZES[i]) { bad = i; break; }
    }
    if (bad < 0 && ws_size < NEED_WS) bad = 90;      // 124.5 MB (proved present)
    if (bad < 0 && out_size != 280000) bad = 95;
    if (bad >= 0) {
        fillf_k<<<(out_size + 255) / 256, 256, 0, stream>>>(
            (float*)d_out, out_size, 500.f + 4.f * bad);
        return;
    }

    const float* z_fs   = (const float*)d_in[0];
    const float* x_fs   = (const float*)d_in[1];
    const float* pre_w  = (const float*)d_in[2];
    const float* pre_g  = (const float*)d_in[3];
    const float* pre_b  = (const float*)d_in[4];
    const float* pre_m  = (const float*)d_in[5];
    const float* pre_v  = (const float*)d_in[6];
    const float* head_w = (const float*)d_in[7];
    const float* head_g = (const float*)d_in[8];
    const float* head_b = (const float*)d_in[9];
    const float* head_m = (const float*)d_in[10];
    const float* head_v = (const float*)d_in[11];
    const float* cls_w1 = (const float*)d_in[12];
    const float* cls_g  = (const float*)d_in[13];
    const float* cls_b  = (const float*)d_in[14];
    const float* cls_m  = (const float*)d_in[15];
    const float* cls_v  = (const float*)d_in[16];
    const float* cls_w2 = (const float*)d_in[17];
    const float* cls_b2 = (const float*)d_in[18];
    const float* loc_w1 = (const float*)d_in[19];
    const float* loc_g  = (const float*)d_in[20];
    const float* loc_b  = (const float*)d_in[21];
    const float* loc_m  = (const float*)d_in[22];
    const float* loc_v  = (const float*)d_in[23];
    const float* loc_w2 = (const float*)d_in[24];
    const float* loc_b2 = (const float*)d_in[25];
    const float* ctr_w1 = (const float*)d_in[26];
    const float* ctr_g  = (const float*)d_in[27];
    const float* ctr_b  = (const float*)d_in[28];
    const float* ctr_m  = (const float*)d_in[29];
    const float* ctr_v  = (const float*)d_in[30];
    const float* ctr_w2 = (const float*)d_in[31];
    const float* ctr_b2 = (const float*)d_in[32];
    const float* w_cls  = (const float*)d_in[33];
    const float* w_loc  = (const float*)d_in[34];
    const float* w_ctr  = (const float*)d_in[35];

    unsigned short* xc   = (unsigned short*)d_ws;
    unsigned short* feat = xc + 3 * stageEl;
    unsigned short* wbf  = feat + 3 * stageEl;

    hipMemsetAsync(d_out, 0, (size_t)OUT_N * sizeof(float), stream);

    wconv_k<<<(4 * 196608 + 255) / 256, 256, 0, stream>>>(
        head_w, cls_w1, loc_w1, ctr_w1, wbf);

    fused_pre_xcorr<<<dim3(B_ * C_ / 2, 3), 256, 0, stream>>>(
        x_fs, z_fs, pre_w, pre_g, pre_b, pre_m, pre_v, xc, 0);

    c1_mfma<<<dim3(2 * 960), 256, 0, stream>>>(
        xc, wbf, head_g, head_b, head_m, head_v, feat);

    heads3_mfma<<<dim3(6 * 960), 256, 0, stream>>>(
        feat, wbf,
        cls_g, cls_b, cls_m, cls_v,
        loc_g, loc_b, loc_m, loc_v,
        ctr_g, ctr_b, ctr_m, ctr_v,
        cls_w2, loc_w2, ctr_w2,
        w_cls, w_loc, w_ctr, (float*)d_out);

    bias_out<<<(OUT_N + 255) / 256, 256, 0, stream>>>(
        (float*)d_out, cls_b2, loc_b2, ctr_b2, w_cls, w_loc, w_ctr);
}